// Round 7
// baseline (218.927 us; speedup 1.0000x reference)
//
#include <hip/hip_runtime.h>
#include <cstdint>
#include <cstddef>

typedef __bf16 bf16;
typedef __bf16 bf16x8 __attribute__((ext_vector_type(8)));
typedef float  f32x4  __attribute__((ext_vector_type(4)));

#define B_  2
#define S_  2048
#define D_  1024
#define H_  16
#define KH  64

// ---------------------------------------------------------------------------
// async global->LDS, 16B per lane. LDS dest = wave-uniform base + lane*16.
// ---------------------------------------------------------------------------
__device__ __forceinline__ void gload_lds16(const bf16* gp, bf16* lds_base) {
    __builtin_amdgcn_global_load_lds(
        (const __attribute__((address_space(1))) unsigned int*)gp,
        (__attribute__((address_space(3))) unsigned int*)lds_base,
        16, 0, 0);
}

// ---------------------------------------------------------------------------
// prep: fused cast_x (blocks 0..4095) + weight transpose (blocks 4096..5119).
// ---------------------------------------------------------------------------
__global__ __launch_bounds__(256) void prep(
    const float* __restrict__ x, bf16* __restrict__ xb,
    const float* __restrict__ Wq, const float* __restrict__ Wk,
    const float* __restrict__ Wv, const float* __restrict__ Wo,
    bf16* __restrict__ WqkvT, bf16* __restrict__ WoT)
{
    __shared__ bf16 tl[64][72];
    int z = blockIdx.x;
    if (z < 4096) {
        const int i = (z * 256 + threadIdx.x) * 4;
        const float4 v = *(const float4*)(x + i);
        union { int2 w; bf16 e[4]; } u;
        u.e[0] = (bf16)v.x; u.e[1] = (bf16)v.y;
        u.e[2] = (bf16)v.z; u.e[3] = (bf16)v.w;
        *(int2*)(xb + i) = u.w;
        return;
    }
    z -= 4096;
    const int zx = z & 15, zy = (z >> 4) & 15, zw = z >> 8;
    const float* src = (zw == 0) ? Wq : (zw == 1) ? Wk : (zw == 2) ? Wv : Wo;
    bf16* dst = (zw < 3) ? (WqkvT + (size_t)zw * D_ * D_) : WoT;
    const int r0 = zy * 64;
    const int c0 = zx * 64;
    const int t  = threadIdx.x;
    {
        const int r = t >> 2, cs = (t & 3) * 16;
        const float4* p = (const float4*)(src + (size_t)(r0 + r) * D_ + c0 + cs);
        float4 a0 = p[0], a1 = p[1], a2 = p[2], a3 = p[3];
        tl[cs +  0][r] = (bf16)a0.x; tl[cs +  1][r] = (bf16)a0.y;
        tl[cs +  2][r] = (bf16)a0.z; tl[cs +  3][r] = (bf16)a0.w;
        tl[cs +  4][r] = (bf16)a1.x; tl[cs +  5][r] = (bf16)a1.y;
        tl[cs +  6][r] = (bf16)a1.z; tl[cs +  7][r] = (bf16)a1.w;
        tl[cs +  8][r] = (bf16)a2.x; tl[cs +  9][r] = (bf16)a2.y;
        tl[cs + 10][r] = (bf16)a2.z; tl[cs + 11][r] = (bf16)a2.w;
        tl[cs + 12][r] = (bf16)a3.x; tl[cs + 13][r] = (bf16)a3.y;
        tl[cs + 14][r] = (bf16)a3.z; tl[cs + 15][r] = (bf16)a3.w;
    }
    __syncthreads();
    {
        const int c = t >> 2, rs = (t & 3) * 16;
        union { int4 v[2]; bf16 e[16]; } u;
#pragma unroll
        for (int i = 0; i < 16; ++i) u.e[i] = tl[c][rs + i];
        int4* p = (int4*)(dst + (size_t)(c0 + c) * D_ + r0 + rs);
        p[0] = u.v[0]; p[1] = u.v[1];
    }
}

// ---------------------------------------------------------------------------
// GEMM C = A(MxKd) * BT(NxKd)^T, bf16 in, fp32 accum. 128xBN tile, BK=64,
// 4 waves (2x2), 16x16x32 MFMA, global_load_lds width-16.
// EPI=0: fp32 row-major store.
// EPI=1 (BN=128): QKV scatter -- q scaled by 0.125*log2(e) (softmax in
// exp2), k plain, v stored TRANSPOSED into (B,H,64,S).
// ---------------------------------------------------------------------------
template <int EPI, int BN>
__global__ __launch_bounds__(256, 2) void gemm_bt(
    const bf16* __restrict__ A, const bf16* __restrict__ BT,
    float* __restrict__ C, int N, int Kd,
    bf16* __restrict__ qp, bf16* __restrict__ kp, bf16* __restrict__ vp)
{
    constexpr int NJF = BN / 32;           // j-frags per wave
    __shared__ bf16 As[128 * 64];
    __shared__ bf16 Bs[BN * 64];
    const int tid  = threadIdx.x;
    const int lane = tid & 63;
    const int wave = tid >> 6;
    const int l15  = lane & 15;
    const int quad = lane >> 4;
    const int m0 = blockIdx.y * 128;
    const int n0 = blockIdx.x * BN;
    const int wm = (wave >> 1) * 64;
    const int wn = (wave & 1) * (BN / 2);

    f32x4 acc[4][NJF];
#pragma unroll
    for (int i = 0; i < 4; ++i)
#pragma unroll
        for (int j = 0; j < NJF; ++j) acc[i][j] = f32x4{0.f, 0.f, 0.f, 0.f};

    for (int k0 = 0; k0 < Kd; k0 += 64) {
        __syncthreads();
#pragma unroll
        for (int c = 0; c < 4; ++c) {
            const int base  = wave * 4096 + c * 1024;
            const int flatb = base + lane * 16;
            const int row   = flatb >> 7;
            const int col   = (flatb & 127) >> 1;
            gload_lds16(A + (size_t)(m0 + row) * Kd + k0 + col, As + (base >> 1));
        }
#pragma unroll
        for (int c = 0; c < NJF; ++c) {
            const int base  = wave * (BN * 32) + c * 1024;
            const int flatb = base + lane * 16;
            const int row   = flatb >> 7;
            const int col   = (flatb & 127) >> 1;
            gload_lds16(BT + (size_t)(n0 + row) * Kd + k0 + col, Bs + (base >> 1));
        }
        __syncthreads();
#pragma unroll
        for (int kk = 0; kk < 64; kk += 32) {
            bf16x8 af[4], bfv[NJF];
#pragma unroll
            for (int i = 0; i < 4; ++i)
                af[i] = *(const bf16x8*)&As[(wm + i * 16 + l15) * 64 + kk + quad * 8];
#pragma unroll
            for (int j = 0; j < NJF; ++j)
                bfv[j] = *(const bf16x8*)&Bs[(wn + j * 16 + l15) * 64 + kk + quad * 8];
#pragma unroll
            for (int i = 0; i < 4; ++i)
#pragma unroll
                for (int j = 0; j < NJF; ++j)
                    acc[i][j] = __builtin_amdgcn_mfma_f32_16x16x32_bf16(
                        af[i], bfv[j], acc[i][j], 0, 0, 0);
        }
    }

#pragma unroll
    for (int i = 0; i < 4; ++i)
#pragma unroll
        for (int j = 0; j < NJF; ++j) {
            const int Rb = m0 + wm + i * 16 + quad * 4;
            const int Cc = n0 + wn + j * 16 + l15;
            if (EPI == 0) {
#pragma unroll
                for (int r = 0; r < 4; ++r)
                    C[(size_t)(Rb + r) * N + Cc] = acc[i][j][r];
            } else {
                const int sec = Cc >> 10, cc = Cc & 1023;
                const int h = cc >> 6, kd = cc & 63;
#pragma unroll
                for (int r = 0; r < 4; ++r) {
                    const int row = Rb + r;
                    const int b = row >> 11, s = row & (S_ - 1);
                    const float v = acc[i][j][r];
                    if (sec == 0)         // q: 1/sqrt(64) * log2(e) for exp2 softmax
                        qp[((size_t)(b * H_ + h) * S_ + s) * KH + kd] =
                            (bf16)(v * 0.1803368801111204f);
                    else if (sec == 1)
                        kp[((size_t)(b * H_ + h) * S_ + s) * KH + kd] = (bf16)v;
                    else                  // v: direct transpose into (B,H,64,S)
                        vp[((size_t)(b * H_ + h) * KH + kd) * S_ + s] = (bf16)v;
                }
            }
        }
}

// ---------------------------------------------------------------------------
// RoPE on first 32 dims of each 64-dim head row, in place, K ONLY (q is
// rope'd in-register inside attn). 65536 rows, 1 thread/row.
// ---------------------------------------------------------------------------
__global__ __launch_bounds__(256) void rope_k(bf16* __restrict__ k)
{
    const int tid = blockIdx.x * blockDim.x + threadIdx.x;  // 65536
    const int s   = tid & (S_ - 1);
    bf16* p = k + (size_t)tid * KH;
    union { int4 v[4]; bf16 e[32]; } u;
    int4* pv = (int4*)p;
#pragma unroll
    for (int i = 0; i < 4; ++i) u.v[i] = pv[i];
    const float l2_10000 = 13.28771237954945f;  // log2(10000)
#pragma unroll
    for (int i = 0; i < 16; ++i) {
        const float inv = exp2f(-(float)i * (l2_10000 / 16.f));
        const float ang = (float)s * inv;
        const float sb = sinf(ang);
        const float cb = cosf(ang);
        const float x0 = (float)u.e[2 * i], x1 = (float)u.e[2 * i + 1];
        u.e[2 * i]     = (bf16)(x0 * cb - x1 * sb);
        u.e[2 * i + 1] = (bf16)(x1 * cb + x0 * sb);
    }
#pragma unroll
    for (int i = 0; i < 4; ++i) pv[i] = u.v[i];
}

// ---------------------------------------------------------------------------
// Flash attention v7 -- all-resident grid. 1024 blocks = 32 bh x 32 q-tiles
// (64 rows); LDS exactly 40960 B -> 4 blocks/CU, the ENTIRE grid is
// co-resident (no dispatch tail; short blocks retire and free issue slots
// for long ones). 4 waves x 16 rows. KV double-buffered via XOR-swizzled
// global_load_lds. Softmax: p = exp2(s) (q pre-scaled by log2 e); row sums
// via a P*ones MFMA (no per-lane adds, no butterfly). Q-RoPE applied
// in-register once per block. Ps XOR-swizzled (no padding).
// ---------------------------------------------------------------------------
__global__ __launch_bounds__(256, 4) void attn(
    const bf16* __restrict__ q, const bf16* __restrict__ k,
    const bf16* __restrict__ vt, bf16* __restrict__ y)
{
    __shared__ bf16 Ks[2][64 * 64];    // [buf][key][dim-group swizzled]
    __shared__ bf16 VTs[2][64 * 64];   // [buf][vdim][key-group swizzled]
    __shared__ bf16 Ps[4][16][64];     // [wave][row][key-group swizzled]

    const int z  = blockIdx.x;         // 0..1023
    const int bh = z >> 5;
    const int qt = z & 31;
    const int b  = bh >> 4, h = bh & 15;
    const int t    = threadIdx.x;
    const int lane = t & 63, wave = t >> 6;
    const int l15  = lane & 15, quad = lane >> 4;
    const int wrow = qt * 64 + wave * 16;      // wave's 16 q-rows

    const bf16* kbh = k  + (size_t)bh * S_ * KH;
    const bf16* vbh = vt + (size_t)bh * KH * S_;

    // staging lane mapping with XOR swizzle (16B granularity)
    const int srow = lane >> 3;              // row within 8-row chunk
    const int sg   = (lane & 7) ^ srow;      // swizzled col-group

    auto stage = [&](int jt, int bb) {
        const int j0 = jt * 64;
#pragma unroll
        for (int i = 0; i < 2; ++i) {
            const int c = wave * 2 + i;      // chunk 0..7 (8 rows each)
            gload_lds16(kbh + (size_t)(j0 + c * 8 + srow) * KH + sg * 8,
                        &Ks[bb][c * 8 * 64]);
            gload_lds16(vbh + (size_t)(c * 8 + srow) * S_ + j0 + sg * 8,
                        &VTs[bb][c * 8 * 64]);
        }
    };

    // Q fragment (A-operand) + in-register RoPE on cols < 32 (all in qf[0]).
    bf16x8 qf[2];
    {
        const bf16* qp = q + ((size_t)bh * S_ + wrow + l15) * KH + quad * 8;
        qf[0] = *(const bf16x8*)qp;
        qf[1] = *(const bf16x8*)(qp + 32);
        const float s = (float)(wrow + l15);
#pragma unroll
        for (int tt = 0; tt < 4; ++tt) {
            const int i = quad * 4 + tt;     // rope pair index 0..15
            const float inv = exp2f(-(float)i * (13.28771237954945f / 16.f));
            const float ang = s * inv;
            const float sn = sinf(ang), cn = cosf(ang);
            const float x0 = (float)qf[0][2 * tt], x1 = (float)qf[0][2 * tt + 1];
            qf[0][2 * tt]     = (bf16)(x0 * cn - x1 * sn);
            qf[0][2 * tt + 1] = (bf16)(x1 * cn + x0 * sn);
        }
    }

    bf16x8 ones;
#pragma unroll
    for (int i = 0; i < 8; ++i) ones[i] = (bf16)1.0f;

    f32x4 accO[4], lacc;
#pragma unroll
    for (int j = 0; j < 4; ++j) accO[j] = f32x4{0.f, 0.f, 0.f, 0.f};
    lacc = f32x4{0.f, 0.f, 0.f, 0.f};

    const int nj = qt + 1;
    stage(0, 0);
    for (int jt = 0; jt < nj; ++jt) {
        const int bb = jt & 1;
        __syncthreads();                       // publishes buf bb
        if (jt + 1 < nj) stage(jt + 1, bb ^ 1);  // in flight during compute

        // S = Q K^T
        f32x4 accS[4];
#pragma unroll
        for (int nb = 0; nb < 4; ++nb) accS[nb] = f32x4{0.f, 0.f, 0.f, 0.f};
#pragma unroll
        for (int c = 0; c < 2; ++c) {
            bf16x8 kf[4];
#pragma unroll
            for (int nb = 0; nb < 4; ++nb)
                kf[nb] = *(const bf16x8*)
                    &Ks[bb][(nb * 16 + l15) * 64 + (((c * 4 + quad) ^ (l15 & 7)) * 8)];
#pragma unroll
            for (int nb = 0; nb < 4; ++nb)
                accS[nb] = __builtin_amdgcn_mfma_f32_16x16x32_bf16(
                    qf[c], kf[nb], accS[nb], 0, 0, 0);
        }

        // causal mask: only the diagonal tile
        if (jt == nj - 1) {
            const int j0 = jt * 64;
#pragma unroll
            for (int nb = 0; nb < 4; ++nb)
#pragma unroll
                for (int r = 0; r < 4; ++r) {
                    const int qi = wrow + quad * 4 + r;
                    const int ki = j0 + nb * 16 + l15;
                    if (ki > qi) accS[nb][r] = -1e30f;
                }
        }

        // p = exp2(s); C->A transpose via wave-private swizzled Ps
#pragma unroll
        for (int nb = 0; nb < 4; ++nb)
#pragma unroll
            for (int r = 0; r < 4; ++r) {
                const float p = __builtin_amdgcn_exp2f(accS[nb][r]);
                const int row = quad * 4 + r;
                Ps[wave][row][(((nb * 2 + (l15 >> 3)) ^ (row & 7)) * 8) + (l15 & 7)]
                    = (bf16)p;
            }

        // O += P V ; lacc += P * ones (row sums, no cross-lane ops)
#pragma unroll
        for (int c = 0; c < 2; ++c) {
            bf16x8 vf[4];
#pragma unroll
            for (int vb = 0; vb < 4; ++vb)
                vf[vb] = *(const bf16x8*)
                    &VTs[bb][(vb * 16 + l15) * 64 + (((c * 4 + quad) ^ (l15 & 7)) * 8)];
            const bf16x8 pf = *(const bf16x8*)
                &Ps[wave][l15][((c * 4 + quad) ^ (l15 & 7)) * 8];
#pragma unroll
            for (int vb = 0; vb < 4; ++vb)
                accO[vb] = __builtin_amdgcn_mfma_f32_16x16x32_bf16(
                    pf, vf[vb], accO[vb], 0, 0, 0);
            lacc = __builtin_amdgcn_mfma_f32_16x16x32_bf16(pf, ones, lacc, 0, 0, 0);
        }
    }

    // normalize and store (lacc[r] already holds the full row sum in every lane)
    float rinv[4];
#pragma unroll
    for (int r = 0; r < 4; ++r) rinv[r] = 1.0f / lacc[r];
#pragma unroll
    for (int vb = 0; vb < 4; ++vb)
#pragma unroll
        for (int r = 0; r < 4; ++r) {
            const int row = wrow + quad * 4 + r;
            const int col = h * KH + vb * 16 + l15;
            y[((size_t)b * S_ + row) * D_ + col] = (bf16)(accO[vb][r] * rinv[r]);
        }
}

// ---------------------------------------------------------------------------
extern "C" void kernel_launch(void* const* d_in, const int* in_sizes, int n_in,
                              void* d_out, int out_size, void* d_ws, size_t ws_size,
                              hipStream_t stream)
{
    (void)in_sizes; (void)n_in; (void)out_size; (void)ws_size;
    const float* x  = (const float*)d_in[0];
    // d_in[1] is the mask: deterministic tril -> causality handled by index
    const float* Wq = (const float*)d_in[2];
    const float* Wk = (const float*)d_in[3];
    const float* Wv = (const float*)d_in[4];
    const float* Wo = (const float*)d_in[5];
    float* out = (float*)d_out;

    char* ws = (char*)d_ws;
    bf16* WqkvT = (bf16*)(ws + 0);          //  6 MB
    bf16* WoT   = (bf16*)(ws + 6291456);    //  2 MB
    bf16* xb    = (bf16*)(ws + 8388608);    //  8 MB (B*S, D)
    bf16* qw    = (bf16*)(ws + 16777216);   //  8 MB (B,H,S,64), scaled (no rope)
    bf16* kw    = (bf16*)(ws + 25165824);   //  8 MB (B,H,S,64)
    bf16* vtw   = (bf16*)(ws + 33554432);   //  8 MB (B,H,64,S), pre-transposed
    bf16* yw    = (bf16*)(ws + 41943040);   //  8 MB (B,S,D)

    hipLaunchKernelGGL(prep, dim3(5120), dim3(256), 0, stream,
                       x, xb, Wq, Wk, Wv, Wo, WqkvT, WoT);
    hipLaunchKernelGGL((gemm_bt<1, 128>), dim3(24, 32), dim3(256), 0, stream,
                       xb, WqkvT, (float*)nullptr, 3072, 1024, qw, kw, vtw);
    hipLaunchKernelGGL(rope_k, dim3(256), dim3(256), 0, stream, kw);
    hipLaunchKernelGGL(attn, dim3(1024), dim3(256), 0, stream, qw, kw, vtw, yw);
    hipLaunchKernelGGL((gemm_bt<0, 64>), dim3(16, 32), dim3(256), 0, stream,
                       yw, WoT, out, 1024, 1024,
                       (bf16*)nullptr, (bf16*)nullptr, (bf16*)nullptr);
}

// Round 8
// 204.663 us; speedup vs baseline: 1.0697x; 1.0697x over previous
//
#include <hip/hip_runtime.h>
#include <cstdint>
#include <cstddef>

typedef __bf16 bf16;
typedef __bf16 bf16x8 __attribute__((ext_vector_type(8)));
typedef float  f32x4  __attribute__((ext_vector_type(4)));

#define B_  2
#define S_  2048
#define D_  1024
#define H_  16
#define KH  64

// ---------------------------------------------------------------------------
// async global->LDS, 16B per lane. LDS dest = wave-uniform base + lane*16.
// ---------------------------------------------------------------------------
__device__ __forceinline__ void gload_lds16(const bf16* gp, bf16* lds_base) {
    __builtin_amdgcn_global_load_lds(
        (const __attribute__((address_space(1))) unsigned int*)gp,
        (__attribute__((address_space(3))) unsigned int*)lds_base,
        16, 0, 0);
}

// ---------------------------------------------------------------------------
// prep: fused cast_x (blocks 0..4095) + weight transpose (blocks 4096..5119).
// ---------------------------------------------------------------------------
__global__ __launch_bounds__(256) void prep(
    const float* __restrict__ x, bf16* __restrict__ xb,
    const float* __restrict__ Wq, const float* __restrict__ Wk,
    const float* __restrict__ Wv, const float* __restrict__ Wo,
    bf16* __restrict__ WqkvT, bf16* __restrict__ WoT)
{
    __shared__ bf16 tl[64][72];
    int z = blockIdx.x;
    if (z < 4096) {
        const int i = (z * 256 + threadIdx.x) * 4;
        const float4 v = *(const float4*)(x + i);
        union { int2 w; bf16 e[4]; } u;
        u.e[0] = (bf16)v.x; u.e[1] = (bf16)v.y;
        u.e[2] = (bf16)v.z; u.e[3] = (bf16)v.w;
        *(int2*)(xb + i) = u.w;
        return;
    }
    z -= 4096;
    const int zx = z & 15, zy = (z >> 4) & 15, zw = z >> 8;
    const float* src = (zw == 0) ? Wq : (zw == 1) ? Wk : (zw == 2) ? Wv : Wo;
    bf16* dst = (zw < 3) ? (WqkvT + (size_t)zw * D_ * D_) : WoT;
    const int r0 = zy * 64;
    const int c0 = zx * 64;
    const int t  = threadIdx.x;
    {
        const int r = t >> 2, cs = (t & 3) * 16;
        const float4* p = (const float4*)(src + (size_t)(r0 + r) * D_ + c0 + cs);
        float4 a0 = p[0], a1 = p[1], a2 = p[2], a3 = p[3];
        tl[cs +  0][r] = (bf16)a0.x; tl[cs +  1][r] = (bf16)a0.y;
        tl[cs +  2][r] = (bf16)a0.z; tl[cs +  3][r] = (bf16)a0.w;
        tl[cs +  4][r] = (bf16)a1.x; tl[cs +  5][r] = (bf16)a1.y;
        tl[cs +  6][r] = (bf16)a1.z; tl[cs +  7][r] = (bf16)a1.w;
        tl[cs +  8][r] = (bf16)a2.x; tl[cs +  9][r] = (bf16)a2.y;
        tl[cs + 10][r] = (bf16)a2.z; tl[cs + 11][r] = (bf16)a2.w;
        tl[cs + 12][r] = (bf16)a3.x; tl[cs + 13][r] = (bf16)a3.y;
        tl[cs + 14][r] = (bf16)a3.z; tl[cs + 15][r] = (bf16)a3.w;
    }
    __syncthreads();
    {
        const int c = t >> 2, rs = (t & 3) * 16;
        union { int4 v[2]; bf16 e[16]; } u;
#pragma unroll
        for (int i = 0; i < 16; ++i) u.e[i] = tl[c][rs + i];
        int4* p = (int4*)(dst + (size_t)(c0 + c) * D_ + r0 + rs);
        p[0] = u.v[0]; p[1] = u.v[1];
    }
}

// ---------------------------------------------------------------------------
// GEMM C = A(MxKd) * BT(NxKd)^T, bf16 in, fp32 accum. 128xBN tile, BK=64,
// 4 waves (2x2), 16x16x32 MFMA, global_load_lds width-16.
// EPI=0: fp32 row-major store.
// EPI=1 (BN=128): QKV scatter -- q scaled by 0.125*log2(e) (softmax in
// exp2), k plain, v stored TRANSPOSED into (B,H,64,S).
// ---------------------------------------------------------------------------
template <int EPI, int BN>
__global__ __launch_bounds__(256, 2) void gemm_bt(
    const bf16* __restrict__ A, const bf16* __restrict__ BT,
    float* __restrict__ C, int N, int Kd,
    bf16* __restrict__ qp, bf16* __restrict__ kp, bf16* __restrict__ vp)
{
    constexpr int NJF = BN / 32;           // j-frags per wave
    __shared__ bf16 As[128 * 64];
    __shared__ bf16 Bs[BN * 64];
    const int tid  = threadIdx.x;
    const int lane = tid & 63;
    const int wave = tid >> 6;
    const int l15  = lane & 15;
    const int quad = lane >> 4;
    const int m0 = blockIdx.y * 128;
    const int n0 = blockIdx.x * BN;
    const int wm = (wave >> 1) * 64;
    const int wn = (wave & 1) * (BN / 2);

    f32x4 acc[4][NJF];
#pragma unroll
    for (int i = 0; i < 4; ++i)
#pragma unroll
        for (int j = 0; j < NJF; ++j) acc[i][j] = f32x4{0.f, 0.f, 0.f, 0.f};

    for (int k0 = 0; k0 < Kd; k0 += 64) {
        __syncthreads();
#pragma unroll
        for (int c = 0; c < 4; ++c) {
            const int base  = wave * 4096 + c * 1024;
            const int flatb = base + lane * 16;
            const int row   = flatb >> 7;
            const int col   = (flatb & 127) >> 1;
            gload_lds16(A + (size_t)(m0 + row) * Kd + k0 + col, As + (base >> 1));
        }
#pragma unroll
        for (int c = 0; c < NJF; ++c) {
            const int base  = wave * (BN * 32) + c * 1024;
            const int flatb = base + lane * 16;
            const int row   = flatb >> 7;
            const int col   = (flatb & 127) >> 1;
            gload_lds16(BT + (size_t)(n0 + row) * Kd + k0 + col, Bs + (base >> 1));
        }
        __syncthreads();
#pragma unroll
        for (int kk = 0; kk < 64; kk += 32) {
            bf16x8 af[4], bfv[NJF];
#pragma unroll
            for (int i = 0; i < 4; ++i)
                af[i] = *(const bf16x8*)&As[(wm + i * 16 + l15) * 64 + kk + quad * 8];
#pragma unroll
            for (int j = 0; j < NJF; ++j)
                bfv[j] = *(const bf16x8*)&Bs[(wn + j * 16 + l15) * 64 + kk + quad * 8];
#pragma unroll
            for (int i = 0; i < 4; ++i)
#pragma unroll
                for (int j = 0; j < NJF; ++j)
                    acc[i][j] = __builtin_amdgcn_mfma_f32_16x16x32_bf16(
                        af[i], bfv[j], acc[i][j], 0, 0, 0);
        }
    }

#pragma unroll
    for (int i = 0; i < 4; ++i)
#pragma unroll
        for (int j = 0; j < NJF; ++j) {
            const int Rb = m0 + wm + i * 16 + quad * 4;
            const int Cc = n0 + wn + j * 16 + l15;
            if (EPI == 0) {
#pragma unroll
                for (int r = 0; r < 4; ++r)
                    C[(size_t)(Rb + r) * N + Cc] = acc[i][j][r];
            } else {
                const int sec = Cc >> 10, cc = Cc & 1023;
                const int h = cc >> 6, kd = cc & 63;
#pragma unroll
                for (int r = 0; r < 4; ++r) {
                    const int row = Rb + r;
                    const int b = row >> 11, s = row & (S_ - 1);
                    const float v = acc[i][j][r];
                    if (sec == 0)         // q: 1/sqrt(64) * log2(e) for exp2 softmax
                        qp[((size_t)(b * H_ + h) * S_ + s) * KH + kd] =
                            (bf16)(v * 0.1803368801111204f);
                    else if (sec == 1)
                        kp[((size_t)(b * H_ + h) * S_ + s) * KH + kd] = (bf16)v;
                    else                  // v: direct transpose into (B,H,64,S)
                        vp[((size_t)(b * H_ + h) * KH + kd) * S_ + s] = (bf16)v;
                }
            }
        }
}

// ---------------------------------------------------------------------------
// RoPE on first 32 dims of each 64-dim head row, in place, K ONLY (q is
// rope'd in-register inside attn). 65536 rows, 1 thread/row.
// ---------------------------------------------------------------------------
__global__ __launch_bounds__(256) void rope_k(bf16* __restrict__ k)
{
    const int tid = blockIdx.x * blockDim.x + threadIdx.x;  // 65536
    const int s   = tid & (S_ - 1);
    bf16* p = k + (size_t)tid * KH;
    union { int4 v[4]; bf16 e[32]; } u;
    int4* pv = (int4*)p;
#pragma unroll
    for (int i = 0; i < 4; ++i) u.v[i] = pv[i];
    const float l2_10000 = 13.28771237954945f;  // log2(10000)
#pragma unroll
    for (int i = 0; i < 16; ++i) {
        const float inv = exp2f(-(float)i * (l2_10000 / 16.f));
        const float ang = (float)s * inv;
        const float sb = sinf(ang);
        const float cb = cosf(ang);
        const float x0 = (float)u.e[2 * i], x1 = (float)u.e[2 * i + 1];
        u.e[2 * i]     = (bf16)(x0 * cb - x1 * sb);
        u.e[2 * i + 1] = (bf16)(x1 * cb + x0 * sb);
    }
#pragma unroll
    for (int i = 0; i < 4; ++i) pv[i] = u.v[i];
}

// ---------------------------------------------------------------------------
// Flash attention v8 -- all-resident grid, per-CU uniform load.
// 1024 blocks; co-resident blocks on a CU are {z, z+256, z+512, z+768}
// (round-robin z%8 -> XCD, (z>>3)%32 -> CU). Decompose z = (w<<8)|(u<<3)|v:
//   bh = u  (all 4 co-resident blocks share the head -> K/V L2 reuse)
//   qt = w==0 ? v : w==1 ? 15-v : w==2 ? 16+v : 31-v
// Per-CU iters = (v+1)+(16-v)+(17+v)+(32-v) = 66, EXACTLY uniform (R7's
// regression was all 4 co-resident blocks sharing one qt -> worst CU 128).
// 4 waves x 16 rows; KV double-buffered XOR-swizzled global_load_lds;
// p = exp2(s) (q pre-scaled by log2 e); row sums via P*ones MFMA;
// q-RoPE in-register. LDS 40960 B -> 4 blocks/CU.
// ---------------------------------------------------------------------------
__global__ __launch_bounds__(256, 4) void attn(
    const bf16* __restrict__ q, const bf16* __restrict__ k,
    const bf16* __restrict__ vt, bf16* __restrict__ y)
{
    __shared__ bf16 Ks[2][64 * 64];    // [buf][key][dim-group swizzled]
    __shared__ bf16 VTs[2][64 * 64];   // [buf][vdim][key-group swizzled]
    __shared__ bf16 Ps[4][16][64];     // [wave][row][key-group swizzled]

    const int z  = blockIdx.x;         // 0..1023
    const int v_ = z & 7;
    const int u_ = (z >> 3) & 31;
    const int w_ = z >> 8;
    const int bh = u_;
    const int qt = (w_ == 0) ? v_ : (w_ == 1) ? (15 - v_)
                 : (w_ == 2) ? (16 + v_) : (31 - v_);
    const int b  = bh >> 4, h = bh & 15;
    const int t    = threadIdx.x;
    const int lane = t & 63, wave = t >> 6;
    const int l15  = lane & 15, quad = lane >> 4;
    const int wrow = qt * 64 + wave * 16;      // wave's 16 q-rows

    const bf16* kbh = k  + (size_t)bh * S_ * KH;
    const bf16* vbh = vt + (size_t)bh * KH * S_;

    // staging lane mapping with XOR swizzle (16B granularity)
    const int srow = lane >> 3;              // row within 8-row chunk
    const int sg   = (lane & 7) ^ srow;      // swizzled col-group

    auto stage = [&](int jt, int bb) {
        const int j0 = jt * 64;
#pragma unroll
        for (int i = 0; i < 2; ++i) {
            const int c = wave * 2 + i;      // chunk 0..7 (8 rows each)
            gload_lds16(kbh + (size_t)(j0 + c * 8 + srow) * KH + sg * 8,
                        &Ks[bb][c * 8 * 64]);
            gload_lds16(vbh + (size_t)(c * 8 + srow) * S_ + j0 + sg * 8,
                        &VTs[bb][c * 8 * 64]);
        }
    };

    // Q fragment (A-operand) + in-register RoPE on cols < 32 (all in qf[0]).
    bf16x8 qf[2];
    {
        const bf16* qp = q + ((size_t)bh * S_ + wrow + l15) * KH + quad * 8;
        qf[0] = *(const bf16x8*)qp;
        qf[1] = *(const bf16x8*)(qp + 32);
        const float s = (float)(wrow + l15);
#pragma unroll
        for (int tt = 0; tt < 4; ++tt) {
            const int i = quad * 4 + tt;     // rope pair index 0..15
            const float inv = exp2f(-(float)i * (13.28771237954945f / 16.f));
            const float ang = s * inv;
            const float sn = sinf(ang), cn = cosf(ang);
            const float x0 = (float)qf[0][2 * tt], x1 = (float)qf[0][2 * tt + 1];
            qf[0][2 * tt]     = (bf16)(x0 * cn - x1 * sn);
            qf[0][2 * tt + 1] = (bf16)(x1 * cn + x0 * sn);
        }
    }

    bf16x8 ones;
#pragma unroll
    for (int i = 0; i < 8; ++i) ones[i] = (bf16)1.0f;

    f32x4 accO[4], lacc;
#pragma unroll
    for (int j = 0; j < 4; ++j) accO[j] = f32x4{0.f, 0.f, 0.f, 0.f};
    lacc = f32x4{0.f, 0.f, 0.f, 0.f};

    const int nj = qt + 1;
    stage(0, 0);
    for (int jt = 0; jt < nj; ++jt) {
        const int bb = jt & 1;
        __syncthreads();                       // publishes buf bb
        if (jt + 1 < nj) stage(jt + 1, bb ^ 1);  // in flight during compute

        // S = Q K^T
        f32x4 accS[4];
#pragma unroll
        for (int nb = 0; nb < 4; ++nb) accS[nb] = f32x4{0.f, 0.f, 0.f, 0.f};
#pragma unroll
        for (int c = 0; c < 2; ++c) {
            bf16x8 kf[4];
#pragma unroll
            for (int nb = 0; nb < 4; ++nb)
                kf[nb] = *(const bf16x8*)
                    &Ks[bb][(nb * 16 + l15) * 64 + (((c * 4 + quad) ^ (l15 & 7)) * 8)];
#pragma unroll
            for (int nb = 0; nb < 4; ++nb)
                accS[nb] = __builtin_amdgcn_mfma_f32_16x16x32_bf16(
                    qf[c], kf[nb], accS[nb], 0, 0, 0);
        }

        // causal mask: only the diagonal tile
        if (jt == nj - 1) {
            const int j0 = jt * 64;
#pragma unroll
            for (int nb = 0; nb < 4; ++nb)
#pragma unroll
                for (int r = 0; r < 4; ++r) {
                    const int qi = wrow + quad * 4 + r;
                    const int ki = j0 + nb * 16 + l15;
                    if (ki > qi) accS[nb][r] = -1e30f;
                }
        }

        // p = exp2(s); C->A transpose via wave-private swizzled Ps
#pragma unroll
        for (int nb = 0; nb < 4; ++nb)
#pragma unroll
            for (int r = 0; r < 4; ++r) {
                const float p = __builtin_amdgcn_exp2f(accS[nb][r]);
                const int row = quad * 4 + r;
                Ps[wave][row][(((nb * 2 + (l15 >> 3)) ^ (row & 7)) * 8) + (l15 & 7)]
                    = (bf16)p;
            }

        // O += P V ; lacc += P * ones (row sums, no cross-lane ops)
#pragma unroll
        for (int c = 0; c < 2; ++c) {
            bf16x8 vf[4];
#pragma unroll
            for (int vb = 0; vb < 4; ++vb)
                vf[vb] = *(const bf16x8*)
                    &VTs[bb][(vb * 16 + l15) * 64 + (((c * 4 + quad) ^ (l15 & 7)) * 8)];
            const bf16x8 pf = *(const bf16x8*)
                &Ps[wave][l15][((c * 4 + quad) ^ (l15 & 7)) * 8];
#pragma unroll
            for (int vb = 0; vb < 4; ++vb)
                accO[vb] = __builtin_amdgcn_mfma_f32_16x16x32_bf16(
                    pf, vf[vb], accO[vb], 0, 0, 0);
            lacc = __builtin_amdgcn_mfma_f32_16x16x32_bf16(pf, ones, lacc, 0, 0, 0);
        }
    }

    // normalize and store (lacc[r] already holds the full row sum in every lane)
    float rinv[4];
#pragma unroll
    for (int r = 0; r < 4; ++r) rinv[r] = 1.0f / lacc[r];
#pragma unroll
    for (int vb = 0; vb < 4; ++vb)
#pragma unroll
        for (int r = 0; r < 4; ++r) {
            const int row = wrow + quad * 4 + r;
            const int col = h * KH + vb * 16 + l15;
            y[((size_t)b * S_ + row) * D_ + col] = (bf16)(accO[vb][r] * rinv[r]);
        }
}

// ---------------------------------------------------------------------------
extern "C" void kernel_launch(void* const* d_in, const int* in_sizes, int n_in,
                              void* d_out, int out_size, void* d_ws, size_t ws_size,
                              hipStream_t stream)
{
    (void)in_sizes; (void)n_in; (void)out_size; (void)ws_size;
    const float* x  = (const float*)d_in[0];
    // d_in[1] is the mask: deterministic tril -> causality handled by index
    const float* Wq = (const float*)d_in[2];
    const float* Wk = (const float*)d_in[3];
    const float* Wv = (const float*)d_in[4];
    const float* Wo = (const float*)d_in[5];
    float* out = (float*)d_out;

    char* ws = (char*)d_ws;
    bf16* WqkvT = (bf16*)(ws + 0);          //  6 MB
    bf16* WoT   = (bf16*)(ws + 6291456);    //  2 MB
    bf16* xb    = (bf16*)(ws + 8388608);    //  8 MB (B*S, D)
    bf16* qw    = (bf16*)(ws + 16777216);   //  8 MB (B,H,S,64), scaled (no rope)
    bf16* kw    = (bf16*)(ws + 25165824);   //  8 MB (B,H,S,64)
    bf16* vtw   = (bf16*)(ws + 33554432);   //  8 MB (B,H,64,S), pre-transposed
    bf16* yw    = (bf16*)(ws + 41943040);   //  8 MB (B,S,D)

    hipLaunchKernelGGL(prep, dim3(5120), dim3(256), 0, stream,
                       x, xb, Wq, Wk, Wv, Wo, WqkvT, WoT);
    hipLaunchKernelGGL((gemm_bt<1, 128>), dim3(24, 32), dim3(256), 0, stream,
                       xb, WqkvT, (float*)nullptr, 3072, 1024, qw, kw, vtw);
    hipLaunchKernelGGL(rope_k, dim3(256), dim3(256), 0, stream, kw);
    hipLaunchKernelGGL(attn, dim3(1024), dim3(256), 0, stream, qw, kw, vtw, yw);
    hipLaunchKernelGGL((gemm_bt<0, 64>), dim3(16, 32), dim3(256), 0, stream,
                       yw, WoT, out, 1024, 1024,
                       (bf16*)nullptr, (bf16*)nullptr, (bf16*)nullptr);
}

// Round 9
// 203.299 us; speedup vs baseline: 1.0769x; 1.0067x over previous
//
#include <hip/hip_runtime.h>
#include <cstdint>
#include <cstddef>

typedef __bf16 bf16;
typedef __bf16 bf16x8 __attribute__((ext_vector_type(8)));
typedef float  f32x4  __attribute__((ext_vector_type(4)));

#define B_  2
#define S_  2048
#define D_  1024
#define H_  16
#define KH  64

// ---------------------------------------------------------------------------
// async global->LDS, 16B per lane. LDS dest = wave-uniform base + lane*16.
// ---------------------------------------------------------------------------
__device__ __forceinline__ void gload_lds16(const bf16* gp, bf16* lds_base) {
    __builtin_amdgcn_global_load_lds(
        (const __attribute__((address_space(1))) unsigned int*)gp,
        (__attribute__((address_space(3))) unsigned int*)lds_base,
        16, 0, 0);
}

// ---------------------------------------------------------------------------
// prep: fused cast_x (blocks 0..4095) + weight transpose (blocks 4096..5119).
// ---------------------------------------------------------------------------
__global__ __launch_bounds__(256) void prep(
    const float* __restrict__ x, bf16* __restrict__ xb,
    const float* __restrict__ Wq, const float* __restrict__ Wk,
    const float* __restrict__ Wv, const float* __restrict__ Wo,
    bf16* __restrict__ WqkvT, bf16* __restrict__ WoT)
{
    __shared__ bf16 tl[64][72];
    int z = blockIdx.x;
    if (z < 4096) {
        const int i = (z * 256 + threadIdx.x) * 4;
        const float4 v = *(const float4*)(x + i);
        union { int2 w; bf16 e[4]; } u;
        u.e[0] = (bf16)v.x; u.e[1] = (bf16)v.y;
        u.e[2] = (bf16)v.z; u.e[3] = (bf16)v.w;
        *(int2*)(xb + i) = u.w;
        return;
    }
    z -= 4096;
    const int zx = z & 15, zy = (z >> 4) & 15, zw = z >> 8;
    const float* src = (zw == 0) ? Wq : (zw == 1) ? Wk : (zw == 2) ? Wv : Wo;
    bf16* dst = (zw < 3) ? (WqkvT + (size_t)zw * D_ * D_) : WoT;
    const int r0 = zy * 64;
    const int c0 = zx * 64;
    const int t  = threadIdx.x;
    {
        const int r = t >> 2, cs = (t & 3) * 16;
        const float4* p = (const float4*)(src + (size_t)(r0 + r) * D_ + c0 + cs);
        float4 a0 = p[0], a1 = p[1], a2 = p[2], a3 = p[3];
        tl[cs +  0][r] = (bf16)a0.x; tl[cs +  1][r] = (bf16)a0.y;
        tl[cs +  2][r] = (bf16)a0.z; tl[cs +  3][r] = (bf16)a0.w;
        tl[cs +  4][r] = (bf16)a1.x; tl[cs +  5][r] = (bf16)a1.y;
        tl[cs +  6][r] = (bf16)a1.z; tl[cs +  7][r] = (bf16)a1.w;
        tl[cs +  8][r] = (bf16)a2.x; tl[cs +  9][r] = (bf16)a2.y;
        tl[cs + 10][r] = (bf16)a2.z; tl[cs + 11][r] = (bf16)a2.w;
        tl[cs + 12][r] = (bf16)a3.x; tl[cs + 13][r] = (bf16)a3.y;
        tl[cs + 14][r] = (bf16)a3.z; tl[cs + 15][r] = (bf16)a3.w;
    }
    __syncthreads();
    {
        const int c = t >> 2, rs = (t & 3) * 16;
        union { int4 v[2]; bf16 e[16]; } u;
#pragma unroll
        for (int i = 0; i < 16; ++i) u.e[i] = tl[c][rs + i];
        int4* p = (int4*)(dst + (size_t)(c0 + c) * D_ + r0 + rs);
        p[0] = u.v[0]; p[1] = u.v[1];
    }
}

// ---------------------------------------------------------------------------
// GEMM C = A(MxKd) * BT(NxKd)^T, bf16 in, fp32 accum. 128xBN tile, BK=64,
// 4 waves (2x2), 16x16x32 MFMA, global_load_lds width-16.
// EPI=0: fp32 row-major store.
// EPI=1 (BN=128): QKV scatter -- q scaled by 0.125*log2(e) (softmax in
// exp2), k with FUSED RoPE (shfl_xor pair rotation, kd<32), v stored
// TRANSPOSED into (B,H,64,S).
// ---------------------------------------------------------------------------
template <int EPI, int BN>
__global__ __launch_bounds__(256, 2) void gemm_bt(
    const bf16* __restrict__ A, const bf16* __restrict__ BT,
    float* __restrict__ C, int N, int Kd,
    bf16* __restrict__ qp, bf16* __restrict__ kp, bf16* __restrict__ vp)
{
    constexpr int NJF = BN / 32;           // j-frags per wave
    __shared__ bf16 As[128 * 64];
    __shared__ bf16 Bs[BN * 64];
    const int tid  = threadIdx.x;
    const int lane = tid & 63;
    const int wave = tid >> 6;
    const int l15  = lane & 15;
    const int quad = lane >> 4;
    const int m0 = blockIdx.y * 128;
    const int n0 = blockIdx.x * BN;
    const int wm = (wave >> 1) * 64;
    const int wn = (wave & 1) * (BN / 2);

    f32x4 acc[4][NJF];
#pragma unroll
    for (int i = 0; i < 4; ++i)
#pragma unroll
        for (int j = 0; j < NJF; ++j) acc[i][j] = f32x4{0.f, 0.f, 0.f, 0.f};

    for (int k0 = 0; k0 < Kd; k0 += 64) {
        __syncthreads();
#pragma unroll
        for (int c = 0; c < 4; ++c) {
            const int base  = wave * 4096 + c * 1024;
            const int flatb = base + lane * 16;
            const int row   = flatb >> 7;
            const int col   = (flatb & 127) >> 1;
            gload_lds16(A + (size_t)(m0 + row) * Kd + k0 + col, As + (base >> 1));
        }
#pragma unroll
        for (int c = 0; c < NJF; ++c) {
            const int base  = wave * (BN * 32) + c * 1024;
            const int flatb = base + lane * 16;
            const int row   = flatb >> 7;
            const int col   = (flatb & 127) >> 1;
            gload_lds16(BT + (size_t)(n0 + row) * Kd + k0 + col, Bs + (base >> 1));
        }
        __syncthreads();
#pragma unroll
        for (int kk = 0; kk < 64; kk += 32) {
            bf16x8 af[4], bfv[NJF];
#pragma unroll
            for (int i = 0; i < 4; ++i)
                af[i] = *(const bf16x8*)&As[(wm + i * 16 + l15) * 64 + kk + quad * 8];
#pragma unroll
            for (int j = 0; j < NJF; ++j)
                bfv[j] = *(const bf16x8*)&Bs[(wn + j * 16 + l15) * 64 + kk + quad * 8];
#pragma unroll
            for (int i = 0; i < 4; ++i)
#pragma unroll
                for (int j = 0; j < NJF; ++j)
                    acc[i][j] = __builtin_amdgcn_mfma_f32_16x16x32_bf16(
                        af[i], bfv[j], acc[i][j], 0, 0, 0);
        }
    }

#pragma unroll
    for (int i = 0; i < 4; ++i)
#pragma unroll
        for (int j = 0; j < NJF; ++j) {
            const int Rb = m0 + wm + i * 16 + quad * 4;
            const int Cc = n0 + wn + j * 16 + l15;
            if (EPI == 0) {
#pragma unroll
                for (int r = 0; r < 4; ++r)
                    C[(size_t)(Rb + r) * N + Cc] = acc[i][j][r];
            } else {
                const int sec = Cc >> 10, cc = Cc & 1023;   // wave-uniform per j
                const int h = cc >> 6, kd = cc & 63;        // kd == j*16 + l15 mod 64
#pragma unroll
                for (int r = 0; r < 4; ++r) {
                    const int row = Rb + r;
                    const int b = row >> 11, s = row & (S_ - 1);
                    float v = acc[i][j][r];
                    if (sec == 0) {       // q: 1/sqrt(64) * log2(e) for exp2 softmax
                        qp[((size_t)(b * H_ + h) * S_ + s) * KH + kd] =
                            (bf16)(v * 0.1803368801111204f);
                    } else if (sec == 1) {  // k: fused RoPE on kd < 32
                        if ((kd >> 4) < 2) {   // wave-uniform (kd>>4 == j&1 pattern)
                            const float partner = __shfl_xor(v, 1);
                            const float inv = __builtin_exp2f(
                                -(float)(kd >> 1) * (13.28771237954945f / 16.f));
                            const float ang = (float)s * inv;
                            float sn, cn;
                            __sincosf(ang, &sn, &cn);
                            v = (l15 & 1) ? fmaf(partner, sn, v * cn)
                                          : fmaf(-partner, sn, v * cn);
                        }
                        kp[((size_t)(b * H_ + h) * S_ + s) * KH + kd] = (bf16)v;
                    } else {              // v: direct transpose into (B,H,64,S)
                        vp[((size_t)(b * H_ + h) * KH + kd) * S_ + s] = (bf16)v;
                    }
                }
            }
        }
}

// ---------------------------------------------------------------------------
// Flash attention v9 -- LDS-traffic-halved. Block = 128 threads (2 waves),
// 64 q-rows; each wave owns 32 rows (2 m-frags) so kf/vf LDS reads amortize
// over 2x the MFMA work (per-block-iter LDS read 74KB -> 40KB).
// 1024 blocks; co-resident blocks on a CU are {z, z+256, z+512, z+768}.
// z = (w<<8)|(u<<3)|v: bh = u (L2 K/V reuse), qt = w==0?v : w==1?15-v :
// w==2?16+v : 31-v  -> per-CU iters = 66, exactly uniform.
// KV double-buffered XOR-swizzled global_load_lds; p = exp2(s) (q pre-scaled
// by log2 e); row sums via P*ones MFMA; q-RoPE in-register.
// LDS = 16+16+8 KB = 40960 B -> 4 blocks/CU (8 waves/CU).
// ---------------------------------------------------------------------------
__global__ __launch_bounds__(128, 2) void attn(
    const bf16* __restrict__ q, const bf16* __restrict__ k,
    const bf16* __restrict__ vt, bf16* __restrict__ y)
{
    __shared__ bf16 Ks[2][64 * 64];    // [buf][key][dim-group swizzled]
    __shared__ bf16 VTs[2][64 * 64];   // [buf][vdim][key-group swizzled]
    __shared__ bf16 Ps[2][2][16][64];  // [wave][mfrag][row][key-group swizzled]

    const int z  = blockIdx.x;         // 0..1023
    const int v_ = z & 7;
    const int u_ = (z >> 3) & 31;
    const int w_ = z >> 8;
    const int bh = u_;
    const int qt = (w_ == 0) ? v_ : (w_ == 1) ? (15 - v_)
                 : (w_ == 2) ? (16 + v_) : (31 - v_);
    const int b  = bh >> 4, h = bh & 15;
    const int t    = threadIdx.x;
    const int lane = t & 63, wave = t >> 6;      // wave in {0,1}
    const int l15  = lane & 15, quad = lane >> 4;
    const int wrow = qt * 64 + wave * 32;        // wave's first q row (32 rows)

    const bf16* kbh = k  + (size_t)bh * S_ * KH;
    const bf16* vbh = vt + (size_t)bh * KH * S_;

    // staging lane mapping with XOR swizzle (16B granularity)
    const int srow = lane >> 3;              // row within 8-row chunk
    const int sg   = (lane & 7) ^ srow;      // swizzled col-group

    auto stage = [&](int jt, int bb) {
        const int j0 = jt * 64;
#pragma unroll
        for (int i = 0; i < 4; ++i) {
            const int c = wave * 4 + i;      // chunk 0..7 (8 rows each)
            gload_lds16(kbh + (size_t)(j0 + c * 8 + srow) * KH + sg * 8,
                        &Ks[bb][c * 8 * 64]);
            gload_lds16(vbh + (size_t)(c * 8 + srow) * S_ + j0 + sg * 8,
                        &VTs[bb][c * 8 * 64]);
        }
    };

    // Q fragments (A-operand) + in-register RoPE on cols < 32 (all in qf[mi][0]).
    bf16x8 qf[2][2];
#pragma unroll
    for (int mi = 0; mi < 2; ++mi) {
        const bf16* qp = q + ((size_t)bh * S_ + wrow + mi * 16 + l15) * KH + quad * 8;
        qf[mi][0] = *(const bf16x8*)qp;
        qf[mi][1] = *(const bf16x8*)(qp + 32);
        const float s = (float)(wrow + mi * 16 + l15);
#pragma unroll
        for (int tt = 0; tt < 4; ++tt) {
            const int i = quad * 4 + tt;     // rope pair index 0..15
            const float inv = exp2f(-(float)i * (13.28771237954945f / 16.f));
            const float ang = s * inv;
            const float sn = sinf(ang), cn = cosf(ang);
            const float x0 = (float)qf[mi][0][2 * tt], x1 = (float)qf[mi][0][2 * tt + 1];
            qf[mi][0][2 * tt]     = (bf16)(x0 * cn - x1 * sn);
            qf[mi][0][2 * tt + 1] = (bf16)(x1 * cn + x0 * sn);
        }
    }

    bf16x8 ones;
#pragma unroll
    for (int i = 0; i < 8; ++i) ones[i] = (bf16)1.0f;

    f32x4 accO[2][4], lacc[2];
#pragma unroll
    for (int mi = 0; mi < 2; ++mi) {
#pragma unroll
        for (int j = 0; j < 4; ++j) accO[mi][j] = f32x4{0.f, 0.f, 0.f, 0.f};
        lacc[mi] = f32x4{0.f, 0.f, 0.f, 0.f};
    }

    const int nj = qt + 1;
    stage(0, 0);
    for (int jt = 0; jt < nj; ++jt) {
        const int bb = jt & 1;
        __syncthreads();                       // publishes buf bb
        if (jt + 1 < nj) stage(jt + 1, bb ^ 1);  // in flight during compute

        // S = Q K^T
        f32x4 accS[2][4];
#pragma unroll
        for (int mi = 0; mi < 2; ++mi)
#pragma unroll
            for (int nb = 0; nb < 4; ++nb) accS[mi][nb] = f32x4{0.f, 0.f, 0.f, 0.f};
#pragma unroll
        for (int c = 0; c < 2; ++c) {
            bf16x8 kf[4];
#pragma unroll
            for (int nb = 0; nb < 4; ++nb)
                kf[nb] = *(const bf16x8*)
                    &Ks[bb][(nb * 16 + l15) * 64 + (((c * 4 + quad) ^ (l15 & 7)) * 8)];
#pragma unroll
            for (int mi = 0; mi < 2; ++mi)
#pragma unroll
                for (int nb = 0; nb < 4; ++nb)
                    accS[mi][nb] = __builtin_amdgcn_mfma_f32_16x16x32_bf16(
                        qf[mi][c], kf[nb], accS[mi][nb], 0, 0, 0);
        }

        // causal mask: only the diagonal tile
        if (jt == nj - 1) {
            const int j0 = jt * 64;
#pragma unroll
            for (int mi = 0; mi < 2; ++mi)
#pragma unroll
                for (int nb = 0; nb < 4; ++nb)
#pragma unroll
                    for (int r = 0; r < 4; ++r) {
                        const int qi = wrow + mi * 16 + quad * 4 + r;
                        const int ki = j0 + nb * 16 + l15;
                        if (ki > qi) accS[mi][nb][r] = -1e30f;
                    }
        }

        // p = exp2(s); C->A transpose via wave-private swizzled Ps
#pragma unroll
        for (int mi = 0; mi < 2; ++mi)
#pragma unroll
            for (int nb = 0; nb < 4; ++nb)
#pragma unroll
                for (int r = 0; r < 4; ++r) {
                    const float p = __builtin_amdgcn_exp2f(accS[mi][nb][r]);
                    const int row = quad * 4 + r;
                    Ps[wave][mi][row][(((nb * 2 + (l15 >> 3)) ^ (row & 7)) * 8) + (l15 & 7)]
                        = (bf16)p;
                }

        // O += P V ; lacc += P * ones (row sums, no cross-lane ops)
#pragma unroll
        for (int c = 0; c < 2; ++c) {
            bf16x8 vf[4];
#pragma unroll
            for (int vb = 0; vb < 4; ++vb)
                vf[vb] = *(const bf16x8*)
                    &VTs[bb][(vb * 16 + l15) * 64 + (((c * 4 + quad) ^ (l15 & 7)) * 8)];
            bf16x8 pf[2];
#pragma unroll
            for (int mi = 0; mi < 2; ++mi)
                pf[mi] = *(const bf16x8*)
                    &Ps[wave][mi][l15][((c * 4 + quad) ^ (l15 & 7)) * 8];
#pragma unroll
            for (int mi = 0; mi < 2; ++mi) {
#pragma unroll
                for (int vb = 0; vb < 4; ++vb)
                    accO[mi][vb] = __builtin_amdgcn_mfma_f32_16x16x32_bf16(
                        pf[mi], vf[vb], accO[mi][vb], 0, 0, 0);
                lacc[mi] = __builtin_amdgcn_mfma_f32_16x16x32_bf16(
                    pf[mi], ones, lacc[mi], 0, 0, 0);
            }
        }
    }

    // normalize and store (lacc[mi][r] holds the full row sum in every lane)
#pragma unroll
    for (int mi = 0; mi < 2; ++mi) {
        float rinv[4];
#pragma unroll
        for (int r = 0; r < 4; ++r) rinv[r] = 1.0f / lacc[mi][r];
#pragma unroll
        for (int vb = 0; vb < 4; ++vb)
#pragma unroll
            for (int r = 0; r < 4; ++r) {
                const int row = wrow + mi * 16 + quad * 4 + r;
                const int col = h * KH + vb * 16 + l15;
                y[((size_t)b * S_ + row) * D_ + col] = (bf16)(accO[mi][vb][r] * rinv[r]);
            }
    }
}

// ---------------------------------------------------------------------------
extern "C" void kernel_launch(void* const* d_in, const int* in_sizes, int n_in,
                              void* d_out, int out_size, void* d_ws, size_t ws_size,
                              hipStream_t stream)
{
    (void)in_sizes; (void)n_in; (void)out_size; (void)ws_size;
    const float* x  = (const float*)d_in[0];
    // d_in[1] is the mask: deterministic tril -> causality handled by index
    const float* Wq = (const float*)d_in[2];
    const float* Wk = (const float*)d_in[3];
    const float* Wv = (const float*)d_in[4];
    const float* Wo = (const float*)d_in[5];
    float* out = (float*)d_out;

    char* ws = (char*)d_ws;
    bf16* WqkvT = (bf16*)(ws + 0);          //  6 MB
    bf16* WoT   = (bf16*)(ws + 6291456);    //  2 MB
    bf16* xb    = (bf16*)(ws + 8388608);    //  8 MB (B*S, D)
    bf16* qw    = (bf16*)(ws + 16777216);   //  8 MB (B,H,S,64), scaled (no rope)
    bf16* kw    = (bf16*)(ws + 25165824);   //  8 MB (B,H,S,64), rope'd
    bf16* vtw   = (bf16*)(ws + 33554432);   //  8 MB (B,H,64,S), pre-transposed
    bf16* yw    = (bf16*)(ws + 41943040);   //  8 MB (B,S,D)

    hipLaunchKernelGGL(prep, dim3(5120), dim3(256), 0, stream,
                       x, xb, Wq, Wk, Wv, Wo, WqkvT, WoT);
    hipLaunchKernelGGL((gemm_bt<1, 128>), dim3(24, 32), dim3(256), 0, stream,
                       xb, WqkvT, (float*)nullptr, 3072, 1024, qw, kw, vtw);
    hipLaunchKernelGGL(attn, dim3(1024), dim3(128), 0, stream, qw, kw, vtw, yw);
    hipLaunchKernelGGL((gemm_bt<0, 64>), dim3(16, 32), dim3(256), 0, stream,
                       yw, WoT, out, 1024, 1024,
                       (bf16*)nullptr, (bf16*)nullptr, (bf16*)nullptr);
}